// Round 1
// baseline (547.011 us; speedup 1.0000x reference)
//
#include <hip/hip_runtime.h>
#include <math.h>

#define B 32
#define S 2048
#define S1 2049
#define D 128
#define H 16
#define DT 2048   // D*H
#define EPS 1e-5f
#define SCALE 0.08838834764831845f  // 1/sqrt(128)

// ---------------------------------------------------------------------------
// Kernel 1: QKV projection.  qkv[b, j] = x[b,:] . Wqkv[j,:] + bqkv[j]
// grid (B, 24), block 256 -> j = by*256+tid in [0, 6144)
// ---------------------------------------------------------------------------
__global__ void __launch_bounds__(256)
qkv_proj_kernel(const float* __restrict__ x,
                const float* __restrict__ Wqkv,
                const float* __restrict__ bqkv,
                float* __restrict__ qkv) {
    const int b = blockIdx.x;
    const int j = blockIdx.y * 256 + threadIdx.x;
    __shared__ float xs[D];
    if (threadIdx.x < D) xs[threadIdx.x] = x[b * D + threadIdx.x];
    __syncthreads();
    const float* w = Wqkv + (size_t)j * D;
    float acc = bqkv[j];
#pragma unroll
    for (int d = 0; d < D; d += 4) {
        float4 w4 = *reinterpret_cast<const float4*>(w + d);
        acc = fmaf(w4.x, xs[d + 0], acc);
        acc = fmaf(w4.y, xs[d + 1], acc);
        acc = fmaf(w4.z, xs[d + 2], acc);
        acc = fmaf(w4.w, xs[d + 3], acc);
    }
    qkv[(size_t)b * (3 * DT) + j] = acc;
}

// ---------------------------------------------------------------------------
// Kernel 2: fused cache-append + single-query attention.
// One block per (b,h).  256 threads = 4 waves = 8 half-waves; each half-wave
// (32 lanes) processes one K/V row per iteration: lane l32 owns float4 at
// column l32 (16B), so a half-wave covers the 512B row exactly.
// Phase A: read K row -> write to out-cache -> dot with q -> score to LDS.
// Softmax over 2049 scores in LDS.
// Phase B: read V row -> write to out-cache -> acc += p * v4.
// ---------------------------------------------------------------------------
__global__ void __launch_bounds__(256)
attn_kernel(const float* __restrict__ past_k,
            const float* __restrict__ past_v,
            const float* __restrict__ qkv,
            float* __restrict__ out_k,
            float* __restrict__ out_v,
            float* __restrict__ yh) {
    const int bh = blockIdx.x;
    const int b = bh / H;
    const int h = bh % H;
    const int tid  = threadIdx.x;
    const int wave = tid >> 6;
    const int lane = tid & 63;
    const int half = lane >> 5;
    const int l32  = lane & 31;
    const int rg   = wave * 2 + half;   // row-group 0..7

    __shared__ float sc[S1];        // scores -> probabilities
    __shared__ float rbuf[256];     // block reductions
    __shared__ float red[8 * D];    // per-row-group PV partials

    const float* qp   = qkv + (size_t)b * (3 * DT) + (size_t)h * D;
    const float* knew = qkv + (size_t)b * (3 * DT) + (size_t)(H + h) * D;
    const float* vnew = qkv + (size_t)b * (3 * DT) + (size_t)(2 * H + h) * D;

    const float4 q4 = reinterpret_cast<const float4*>(qp)[l32];

    const float* kin  = past_k + (size_t)(b * H + h) * S  * D;
    const float* vin  = past_v + (size_t)(b * H + h) * S  * D;
    float*       kout = out_k  + (size_t)(b * H + h) * S1 * D;
    float*       vout = out_v  + (size_t)(b * H + h) * S1 * D;

    // ---- Phase A: K copy + scores ----
    for (int s = rg; s < S1; s += 8) {
        float4 k4;
        if (s < S) k4 = reinterpret_cast<const float4*>(kin + (size_t)s * D)[l32];
        else       k4 = reinterpret_cast<const float4*>(knew)[l32];
        reinterpret_cast<float4*>(kout + (size_t)s * D)[l32] = k4;
        float p = q4.x * k4.x + q4.y * k4.y + q4.z * k4.z + q4.w * k4.w;
        // reduce across the 32 lanes of this half-wave
        p += __shfl_xor(p, 1);
        p += __shfl_xor(p, 2);
        p += __shfl_xor(p, 4);
        p += __shfl_xor(p, 8);
        p += __shfl_xor(p, 16);
        if (l32 == 0) sc[s] = p * SCALE;
    }
    __syncthreads();

    // ---- softmax over sc[0..S1) ----
    float m = -1e30f;
    for (int i = tid; i < S1; i += 256) m = fmaxf(m, sc[i]);
    rbuf[tid] = m;
    __syncthreads();
    for (int off = 128; off > 0; off >>= 1) {
        if (tid < off) rbuf[tid] = fmaxf(rbuf[tid], rbuf[tid + off]);
        __syncthreads();
    }
    m = rbuf[0];
    __syncthreads();

    float lsum = 0.f;
    for (int i = tid; i < S1; i += 256) {
        float e = expf(sc[i] - m);
        sc[i] = e;
        lsum += e;
    }
    rbuf[tid] = lsum;
    __syncthreads();
    for (int off = 128; off > 0; off >>= 1) {
        if (tid < off) rbuf[tid] += rbuf[tid + off];
        __syncthreads();
    }
    const float inv = 1.0f / rbuf[0];
    __syncthreads();

    // ---- Phase B: V copy + PV accumulation ----
    float4 acc = make_float4(0.f, 0.f, 0.f, 0.f);
    for (int s = rg; s < S1; s += 8) {
        float4 v4;
        if (s < S) v4 = reinterpret_cast<const float4*>(vin + (size_t)s * D)[l32];
        else       v4 = reinterpret_cast<const float4*>(vnew)[l32];
        reinterpret_cast<float4*>(vout + (size_t)s * D)[l32] = v4;
        const float p = sc[s];
        acc.x = fmaf(p, v4.x, acc.x);
        acc.y = fmaf(p, v4.y, acc.y);
        acc.z = fmaf(p, v4.z, acc.z);
        acc.w = fmaf(p, v4.w, acc.w);
    }
    reinterpret_cast<float4*>(red)[rg * 32 + l32] = acc;
    __syncthreads();

    if (tid < D) {
        float s = 0.f;
#pragma unroll
        for (int g = 0; g < 8; ++g) s += red[g * D + tid];
        yh[(size_t)(b * H + h) * D + tid] = s * inv;
    }
}

// ---------------------------------------------------------------------------
// Kernel 3: out projection + bias + residual + LayerNorm.  One block per b,
// 128 threads, thread d computes out[b,d].
// ---------------------------------------------------------------------------
__global__ void __launch_bounds__(128)
out_proj_kernel(const float* __restrict__ x,
                const float* __restrict__ yh,
                const float* __restrict__ Wout,
                const float* __restrict__ bout,
                float* __restrict__ out) {
    const int b = blockIdx.x;
    const int d = threadIdx.x;   // 0..127
    __shared__ float ys[DT];     // 8 KB
    __shared__ float tb[D];

    for (int j = d; j < DT; j += D) ys[j] = yh[(size_t)b * DT + j];
    __syncthreads();

    const float* w = Wout + (size_t)d * DT;
    float acc = bout[d];
    for (int j = 0; j < DT; j += 4) {
        float4 w4 = *reinterpret_cast<const float4*>(w + j);
        acc = fmaf(w4.x, ys[j + 0], acc);
        acc = fmaf(w4.y, ys[j + 1], acc);
        acc = fmaf(w4.z, ys[j + 2], acc);
        acc = fmaf(w4.w, ys[j + 3], acc);
    }
    acc += x[b * D + d];   // residual

    // LayerNorm over 128
    tb[d] = acc;
    __syncthreads();
    for (int off = 64; off > 0; off >>= 1) {
        if (d < off) tb[d] += tb[d + off];
        __syncthreads();
    }
    const float mu = tb[0] * (1.0f / D);
    __syncthreads();
    const float diff = acc - mu;
    tb[d] = diff * diff;
    __syncthreads();
    for (int off = 64; off > 0; off >>= 1) {
        if (d < off) tb[d] += tb[d + off];
        __syncthreads();
    }
    const float var = tb[0] * (1.0f / D);
    out[(size_t)b * D + d] = diff / sqrtf(var + EPS);
}

// ---------------------------------------------------------------------------
extern "C" void kernel_launch(void* const* d_in, const int* in_sizes, int n_in,
                              void* d_out, int out_size, void* d_ws, size_t ws_size,
                              hipStream_t stream) {
    const float* x      = (const float*)d_in[0];
    const float* past_k = (const float*)d_in[1];
    const float* past_v = (const float*)d_in[2];
    const float* Wqkv   = (const float*)d_in[3];
    const float* bqkv   = (const float*)d_in[4];
    const float* Wout   = (const float*)d_in[5];
    const float* bout   = (const float*)d_in[6];

    float* out   = (float*)d_out;                       // (B,1,D) = 4096
    float* out_k = out + (size_t)B * D;                 // (B,H,S1,D)
    float* out_v = out_k + (size_t)B * H * S1 * D;      // (B,H,S1,D)

    float* qkv = (float*)d_ws;                          // B * 3*DT floats
    float* yh  = qkv + (size_t)B * 3 * DT;              // B * DT floats

    qkv_proj_kernel<<<dim3(B, (3 * DT) / 256), 256, 0, stream>>>(x, Wqkv, bqkv, qkv);
    attn_kernel<<<B * H, 256, 0, stream>>>(past_k, past_v, qkv, out_k, out_v, yh);
    out_proj_kernel<<<B, D, 0, stream>>>(x, yh, Wout, bout, out);
}

// Round 2
// 493.925 us; speedup vs baseline: 1.1075x; 1.1075x over previous
//
#include <hip/hip_runtime.h>
#include <math.h>

#define B 32
#define S 2048
#define S1 2049
#define D 128
#define H 16
#define DT 2048   // D*H
#define NS 4      // sequence splits per (b,h)
#define ROWS_PER_SPLIT 512
#define EPS 1e-5f
#define SCALE 0.08838834764831845f  // 1/sqrt(128)

typedef float f4v __attribute__((ext_vector_type(4)));

// ---------------------------------------------------------------------------
// Kernel 1: QKV projection + new-token cache append.
// qkv[b, j] = x[b,:] . Wqkv[j,:] + bqkv[j];  j in [0, 6144)
// j in [2048,4096): also write k_new to out_k row 2048
// j in [4096,6144): also write v_new to out_v row 2048
// ---------------------------------------------------------------------------
__global__ void __launch_bounds__(256)
qkv_proj_kernel(const float* __restrict__ x,
                const float* __restrict__ Wqkv,
                const float* __restrict__ bqkv,
                float* __restrict__ qkv,
                float* __restrict__ out_k,
                float* __restrict__ out_v) {
    const int b = blockIdx.x;
    const int j = blockIdx.y * 256 + threadIdx.x;
    __shared__ float xs[D];
    if (threadIdx.x < D) xs[threadIdx.x] = x[b * D + threadIdx.x];
    __syncthreads();
    const float* w = Wqkv + (size_t)j * D;
    float acc = bqkv[j];
#pragma unroll
    for (int d = 0; d < D; d += 4) {
        float4 w4 = *reinterpret_cast<const float4*>(w + d);
        acc = fmaf(w4.x, xs[d + 0], acc);
        acc = fmaf(w4.y, xs[d + 1], acc);
        acc = fmaf(w4.z, xs[d + 2], acc);
        acc = fmaf(w4.w, xs[d + 3], acc);
    }
    qkv[(size_t)b * (3 * DT) + j] = acc;

    if (j >= DT) {
        const int r = j - DT;          // 0 .. 2*DT
        const int which = r >> 11;     // 0 = K, 1 = V
        const int hd = r & (DT - 1);   // h*128 + d
        const int h = hd >> 7;
        const int d = hd & 127;
        float* dst = which ? out_v : out_k;
        dst[((size_t)(b * H + h) * S1 + S) * D + d] = acc;
    }
}

// ---------------------------------------------------------------------------
// Kernel 2: fused cache-copy + single-pass online-softmax attention partials.
// Grid: B*H*NS blocks, 256 threads = 8 half-waves.  Each half-wave owns rows
// s = split*512 + rg + 8k (k=0..63); lane l32 owns the 16B at column l32.
// Per row: load K -> store to cache -> dot(q,k) (butterfly, all lanes get p)
//          load V -> store to cache -> online-rescaled acc += e^(p-m) * v.
// Block-combines 8 rowgroup partials -> (M, L, acc[128]) to workspace.
// ---------------------------------------------------------------------------
__global__ void __launch_bounds__(256)
attn_kernel(const float* __restrict__ past_k,
            const float* __restrict__ past_v,
            const float* __restrict__ qkv,
            float* __restrict__ out_k,
            float* __restrict__ out_v,
            float* __restrict__ part_ml,
            float* __restrict__ part_acc) {
    const int bx = blockIdx.x;
    const int split = bx & (NS - 1);
    const int bh = bx >> 2;
    const int b = bh >> 4;
    const int h = bh & (H - 1);
    const int tid  = threadIdx.x;
    const int wave = tid >> 6;
    const int lane = tid & 63;
    const int half = lane >> 5;
    const int l32  = lane & 31;
    const int rg   = wave * 2 + half;   // 0..7

    const f4v* __restrict__ kin  = (const f4v*)past_k + (size_t)(b * H + h) * S * 32;
    const f4v* __restrict__ vin  = (const f4v*)past_v + (size_t)(b * H + h) * S * 32;
    f4v* __restrict__ kout = (f4v*)out_k + (size_t)(b * H + h) * S1 * 32;
    f4v* __restrict__ vout = (f4v*)out_v + (size_t)(b * H + h) * S1 * 32;

    const f4v q4 = ((const f4v*)qkv)[(size_t)b * (3 * DT / 4) + h * 32 + l32];

    const int s0 = split * ROWS_PER_SPLIT + rg;

    float m = -1e30f;
    float l = 0.f;
    f4v acc = (f4v){0.f, 0.f, 0.f, 0.f};

#pragma unroll 4
    for (int it = 0; it < ROWS_PER_SPLIT / 8; ++it) {
        const int s = s0 + it * 8;
        const size_t off = (size_t)s * 32 + l32;
        f4v k4 = __builtin_nontemporal_load(&kin[off]);
        __builtin_nontemporal_store(k4, &kout[off]);
        f4v t = k4 * q4;
        float p = t.x + t.y + t.z + t.w;
        p += __shfl_xor(p, 1);
        p += __shfl_xor(p, 2);
        p += __shfl_xor(p, 4);
        p += __shfl_xor(p, 8);
        p += __shfl_xor(p, 16);
        p *= SCALE;
        f4v v4 = __builtin_nontemporal_load(&vin[off]);
        __builtin_nontemporal_store(v4, &vout[off]);
        const float mn = fmaxf(m, p);
        const float c = __expf(m - mn);
        const float e = __expf(p - mn);
        l = l * c + e;
        acc = acc * c;
        acc += v4 * e;
        m = mn;
    }

    // ---- block combine over 8 rowgroups ----
    __shared__ float sm[8];
    __shared__ float sl[8];
    __shared__ float sacc[8 * D];
    ((f4v*)sacc)[rg * 32 + l32] = acc;
    if (l32 == 0) { sm[rg] = m; sl[rg] = l; }
    __syncthreads();

    if (tid < D) {
        float M = sm[0];
#pragma unroll
        for (int g = 1; g < 8; ++g) M = fmaxf(M, sm[g]);
        float L = 0.f, y = 0.f;
#pragma unroll
        for (int g = 0; g < 8; ++g) {
            const float wgt = __expf(sm[g] - M);
            L += wgt * sl[g];
            y = fmaf(wgt, sacc[g * D + tid], y);
        }
        part_acc[(size_t)bx * D + tid] = y;
        if (tid == 0) {
            part_ml[2 * bx + 0] = M;
            part_ml[2 * bx + 1] = L;
        }
    }
}

// ---------------------------------------------------------------------------
// Kernel 3: combine partials (+ new-token contribution) -> y_heads, then
// out-proj + bias + residual + LayerNorm.  One block per b, 1024 threads.
// Prologue: wave w handles head h=w; 64 lanes compute dot(q,k_new) and the
// 5-way softmax combine for 2 dims each.
// GEMV: thread t -> output d=t>>3, j-chunk sub=t&7 (256 j each).
// ---------------------------------------------------------------------------
__global__ void __launch_bounds__(1024)
out_proj_kernel(const float* __restrict__ x,
                const float* __restrict__ qkv,
                const float* __restrict__ part_ml,
                const float* __restrict__ part_acc,
                const float* __restrict__ Wout,
                const float* __restrict__ bout,
                float* __restrict__ out) {
    const int b = blockIdx.x;
    const int t = threadIdx.x;
    __shared__ float ys[DT];        // combined attention output, 8 KB
    __shared__ float pp[D * 8];     // GEMV partials, 4 KB
    __shared__ float tb[D];

    // ---- combine phase: wave w = head h ----
    {
        const int h = t >> 6;
        const int lane = t & 63;
        const float* qp   = qkv + (size_t)b * (3 * DT) + h * D;
        const float* knew = qp + DT;
        const float* vnew = qp + 2 * DT;
        // dot(q, k_new)
        float pd = qp[2 * lane] * knew[2 * lane] + qp[2 * lane + 1] * knew[2 * lane + 1];
        pd += __shfl_xor(pd, 1);
        pd += __shfl_xor(pd, 2);
        pd += __shfl_xor(pd, 4);
        pd += __shfl_xor(pd, 8);
        pd += __shfl_xor(pd, 16);
        pd += __shfl_xor(pd, 32);
        const float s = pd * SCALE;

        const int bh = b * H + h;
        float m0 = part_ml[2 * (bh * NS + 0)], l0 = part_ml[2 * (bh * NS + 0) + 1];
        float m1 = part_ml[2 * (bh * NS + 1)], l1 = part_ml[2 * (bh * NS + 1) + 1];
        float m2 = part_ml[2 * (bh * NS + 2)], l2 = part_ml[2 * (bh * NS + 2) + 1];
        float m3 = part_ml[2 * (bh * NS + 3)], l3 = part_ml[2 * (bh * NS + 3) + 1];
        float M = fmaxf(fmaxf(fmaxf(m0, m1), fmaxf(m2, m3)), s);
        const float w0 = __expf(m0 - M), w1 = __expf(m1 - M);
        const float w2 = __expf(m2 - M), w3 = __expf(m3 - M);
        const float wn = __expf(s - M);
        const float L = w0 * l0 + w1 * l1 + w2 * l2 + w3 * l3 + wn;
        const float invL = 1.0f / L;
#pragma unroll
        for (int r = 0; r < 2; ++r) {
            const int d = lane + r * 64;
            float y = wn * vnew[d];
            y = fmaf(w0, part_acc[(size_t)(bh * NS + 0) * D + d], y);
            y = fmaf(w1, part_acc[(size_t)(bh * NS + 1) * D + d], y);
            y = fmaf(w2, part_acc[(size_t)(bh * NS + 2) * D + d], y);
            y = fmaf(w3, part_acc[(size_t)(bh * NS + 3) * D + d], y);
            ys[h * D + d] = y * invL;
        }
    }
    __syncthreads();

    // ---- GEMV: out[d] = Wout[d,:] . ys + bout[d] ----
    {
        const int d = t >> 3;
        const int sub = t & 7;
        const float* w = Wout + (size_t)d * DT + sub * 256;
        const float* y = ys + sub * 256;
        float acc = 0.f;
#pragma unroll
        for (int j = 0; j < 256; j += 4) {
            float4 w4 = *reinterpret_cast<const float4*>(w + j);
            acc = fmaf(w4.x, y[j + 0], acc);
            acc = fmaf(w4.y, y[j + 1], acc);
            acc = fmaf(w4.z, y[j + 2], acc);
            acc = fmaf(w4.w, y[j + 3], acc);
        }
        pp[d * 8 + sub] = acc;
    }
    __syncthreads();

    // ---- reduce + bias + residual + LayerNorm (threads 0..127 active) ----
    float val = 0.f;
    if (t < D) {
        float a = 0.f;
#pragma unroll
        for (int g = 0; g < 8; ++g) a += pp[t * 8 + g];
        val = a + bout[t] + x[b * D + t];
        tb[t] = val;
    }
    __syncthreads();
    for (int off = 64; off > 0; off >>= 1) {
        if (t < off) tb[t] += tb[t + off];
        __syncthreads();
    }
    const float mu = tb[0] * (1.0f / D);
    __syncthreads();
    const float diff = val - mu;
    if (t < D) tb[t] = diff * diff;
    __syncthreads();
    for (int off = 64; off > 0; off >>= 1) {
        if (t < off) tb[t] += tb[t + off];
        __syncthreads();
    }
    const float var = tb[0] * (1.0f / D);
    if (t < D) out[(size_t)b * D + t] = diff / sqrtf(var + EPS);
}

// ---------------------------------------------------------------------------
extern "C" void kernel_launch(void* const* d_in, const int* in_sizes, int n_in,
                              void* d_out, int out_size, void* d_ws, size_t ws_size,
                              hipStream_t stream) {
    const float* x      = (const float*)d_in[0];
    const float* past_k = (const float*)d_in[1];
    const float* past_v = (const float*)d_in[2];
    const float* Wqkv   = (const float*)d_in[3];
    const float* bqkv   = (const float*)d_in[4];
    const float* Wout   = (const float*)d_in[5];
    const float* bout   = (const float*)d_in[6];

    float* out   = (float*)d_out;                       // (B,1,D)
    float* out_k = out + (size_t)B * D;                 // (B,H,S1,D)
    float* out_v = out_k + (size_t)B * H * S1 * D;      // (B,H,S1,D)

    float* qkv      = (float*)d_ws;                     // B*3*DT
    float* part_ml  = qkv + (size_t)B * 3 * DT;         // 2*B*H*NS
    float* part_acc = part_ml + 2 * B * H * NS;         // B*H*NS*D

    qkv_proj_kernel<<<dim3(B, (3 * DT) / 256), 256, 0, stream>>>(
        x, Wqkv, bqkv, qkv, out_k, out_v);
    attn_kernel<<<B * H * NS, 256, 0, stream>>>(
        past_k, past_v, qkv, out_k, out_v, part_ml, part_acc);
    out_proj_kernel<<<B, 1024, 0, stream>>>(
        x, qkv, part_ml, part_acc, Wout, bout, out);
}